// Round 9
// baseline (264.128 us; speedup 1.0000x reference)
//
#include <hip/hip_runtime.h>

// ---------- helpers ----------
__device__ __forceinline__ float2 cmul(float2 a, float2 b){
    return make_float2(a.x*b.x - a.y*b.y, a.x*b.y + a.y*b.x);
}
__device__ __forceinline__ float2 cadd(float2 a, float2 b){
    return make_float2(a.x + b.x, a.y + b.y);
}
__device__ __forceinline__ unsigned short f2h(float f){
    _Float16 h = (_Float16)f;                    // v_cvt_f16_f32, round-nearest
    return __builtin_bit_cast(unsigned short, h);
}

typedef _Float16 f16x8 __attribute__((ext_vector_type(8)));
typedef float    f32x4 __attribute__((ext_vector_type(4)));

// hi/lo fp16 split of 8 contiguous f32 from LDS (kept only for the x input).
__device__ __forceinline__ void split8(const float* p, f16x8& ah, f16x8& al){
    const f32x4* q = (const f32x4*)p;
    f32x4 v0 = q[0], v1 = q[1];
    float av[8] = {v0[0],v0[1],v0[2],v0[3],v1[0],v1[1],v1[2],v1[3]};
    #pragma unroll
    for (int j=0;j<8;++j){
        _Float16 h = (_Float16)av[j];
        ah[j] = h;
        al[j] = (_Float16)(av[j] - (float)h);
    }
}

// Effective per-qubit operator (reference einsum applies U^T):
// G = RZ * RY(-t) * RX.
__device__ __forceinline__ void build_gates(const float* qw, int l, int c, float2 (*G)[2][2]){
    if (c < 8){
        int i = c;
        float t0 = 0.5f*qw[l*24 + i*3 + 0];
        float t1 = 0.5f*qw[l*24 + i*3 + 1];
        float t2 = 0.5f*qw[l*24 + i*3 + 2];
        float c1,s1,c2,s2,c3,s3;
        sincosf(t0,&s1,&c1); sincosf(t1,&s2,&c2); sincosf(t2,&s3,&c3);
        float2 RX[2][2] = {{{c1,0.f},{0.f,-s1}},{{0.f,-s1},{c1,0.f}}};
        // RY^T (transposed: sine sign flipped)
        float2 RY[2][2] = {{{c2,0.f},{s2,0.f}},{{-s2,0.f},{c2,0.f}}};
        float2 M[2][2];
        #pragma unroll
        for (int r=0;r<2;++r)
            #pragma unroll
            for (int cc=0;cc<2;++cc)
                M[r][cc] = cadd(cmul(RY[r][0],RX[0][cc]), cmul(RY[r][1],RX[1][cc]));
        float2 e  = {c3,-s3};
        float2 ec = {c3, s3};
        G[i][0][0]=cmul(e, M[0][0]); G[i][0][1]=cmul(e, M[0][1]);
        G[i][1][0]=cmul(ec,M[1][0]); G[i][1][1]=cmul(ec,M[1][1]);
    }
}
__device__ __forceinline__ int cnot_perm(int k){
    int r = k;
    for (int i=6;i>=0;--i)
        for (int j=7;j>i;--j)
            if ((r >> (7-i)) & 1) r ^= 1 << (7-j);
    return r;
}

// ---------- K1: build layer-0/1 operators + (y==2) BN-folded weight prep ----
__global__ void k_build_prep(const float* __restrict__ qw, float2* __restrict__ U,
                       const float* __restrict__ W1, const float* __restrict__ b1,
                       const float* __restrict__ g1, const float* __restrict__ bt1,
                       const float* __restrict__ m1, const float* __restrict__ v1,
                       const float* __restrict__ W2, const float* __restrict__ b2,
                       const float* __restrict__ g2, const float* __restrict__ bt2,
                       const float* __restrict__ m2, const float* __restrict__ v2,
                       const float* __restrict__ W3,
                       unsigned short* __restrict__ H1w, float* __restrict__ c1,
                       unsigned short* __restrict__ H2w, float* __restrict__ c2,
                       unsigned short* __restrict__ H3w){
    if (blockIdx.y == 2){
        if (blockIdx.x >= 8) return;
        int tid = blockIdx.x*256 + threadIdx.x;
        const int stride = 8*256;
        for (int i=tid; i<4096; i+=stride){ int n=i>>5, k=i&31;
            float s=g1[n]*rsqrtf(v1[n]+1e-5f);
            H1w[i] = f2h(k<16 ? W1[n*16+k]*s : 0.f); }
        for (int i=tid; i<128;  i+=stride){ float s=g1[i]*rsqrtf(v1[i]+1e-5f); c1[i]=(b1[i]-m1[i])*s+bt1[i]; }
        for (int i=tid; i<8192; i+=stride){ int n=i>>7;
            float s=g2[n]*rsqrtf(v2[n]+1e-5f);
            H2w[i] = f2h(W2[i]*s); }
        for (int i=tid; i<64;   i+=stride){ float s=g2[i]*rsqrtf(v2[i]+1e-5f); c2[i]=(b2[i]-m2[i])*s+bt2[i]; }
        for (int i=tid; i<1024; i+=stride){ int n=i>>6, k=i&63;
            H3w[i] = f2h(n<8 ? W3[n*64+k] : 0.f); }
        return;
    }
    __shared__ float2 G[8][2][2];
    int l = blockIdx.y, k = blockIdx.x, c = threadIdx.x;
    build_gates(qw, l, c, G);
    __syncthreads();
    int r = cnot_perm(k);
    float2 p = {1.f, 0.f};
    #pragma unroll
    for (int i=0;i<8;++i)
        p = cmul(p, G[i][(r>>(7-i))&1][(c>>(7-i))&1]);
    U[l*65536 + k*256 + c] = p;
}

// ---------- K2: per-row W = row_r(U3*U2*U1) -> fp16, FRAGMENT-SWIZZLED ------
// element (n,k) -> WqS[((T*8+ks)*64 + lane)*8 + j]; a wave's B-load is then
// base + lane*16B: one contiguous 1KB burst (R7: cut k_main 66->51us).
__global__ __launch_bounds__(256) void k_rowmm(const float* __restrict__ qw,
                                              const float2* __restrict__ U,
                                              unsigned short* __restrict__ WqS){
    __shared__ float2 G[8][2][2];
    __shared__ float2 vs[256];
    __shared__ float2 ws[256];
    int r = blockIdx.x, c = threadIdx.x;
    build_gates(qw, 2, c, G);
    __syncthreads();
    int pr = cnot_perm(r);
    float2 p = {1.f, 0.f};
    #pragma unroll
    for (int i=0;i<8;++i)
        p = cmul(p, G[i][(pr>>(7-i))&1][(c>>(7-i))&1]);
    vs[c] = p;
    __syncthreads();
    float2 acc = {0.f,0.f};
    #pragma unroll 8
    for (int m=0;m<256;++m)
        acc = cadd(acc, cmul(vs[m], U[65536 + m*256 + c]));   // U2
    ws[c] = acc;
    __syncthreads();
    float2 z = {0.f,0.f};
    #pragma unroll 8
    for (int m=0;m<256;++m)
        z = cadd(z, cmul(ws[m], U[m*256 + c]));               // U1
    int T = r >> 4, l15 = r & 15;
    int ks = c >> 5, lq = (c >> 3) & 3, j = c & 7;
    int lane = lq*16 + l15;
    WqS[((T     *8 + ks)*64 + lane)*8 + j] = f2h(z.x);   // Re tiles 0..15
    WqS[(((T+16)*8 + ks)*64 + lane)*8 + j] = f2h(z.y);   // Im tiles 16..31
}

// ---------- K3: FUSED front MLP + s0-expand + quantum GEMM + Z + back MLP --
// 1024 wgs x 256 thr, 64 batch rows/wg. 44.9 KB arena -> 3 wgs/CU (R9).
// front: H1@0 [64][136]f16, H2@17408 [64][72]f16, XS@26624 [64][36]f32,
//        preL@35840 [64][8]f32
// main:  As@0 [64][264]f16; probs@0 [32][269]f32; qacc@34432 [256][9]f32
//        (stride 9: coprime w/ 32 banks, R8 had 8-16-way conflicts at stride 8);
//        qout@43648 [64][9]f32.  Total 45952 B.
#define A_STRIDE 264
#define P_STRIDE 269
__global__ __launch_bounds__(256,3) void k_fused(
    const float* __restrict__ x,
    const unsigned short* __restrict__ H1w, const float* __restrict__ c1,
    const unsigned short* __restrict__ H2w, const float* __restrict__ c2,
    const unsigned short* __restrict__ H3w, const float* __restrict__ b3,
    const unsigned short* __restrict__ WqS,
    const float* __restrict__ W4, const float* __restrict__ b4, const float* __restrict__ g4,
    const float* __restrict__ bt4, const float* __restrict__ m4, const float* __restrict__ v4,
    const float* __restrict__ W5, const float* __restrict__ b5,
    const float* __restrict__ W6, const float* __restrict__ b6,
    float* __restrict__ out)
{
    __shared__ __align__(16) char smem[45952];
    unsigned short* H1 = (unsigned short*)smem;            // [64][136] f16
    unsigned short* H2 = (unsigned short*)(smem + 17408);  // [64][72]  f16
    float* XS   = (float*)(smem + 26624);                  // [64][36]  f32
    float* preL = (float*)(smem + 35840);                  // [64][8]   f32
    unsigned short* As = (unsigned short*)smem;            // [64][264] f16
    float* probs = (float*)smem;                           // [32][269] f32
    float* qacc  = (float*)(smem + 34432);                 // [256][9]  f32
    float* qout  = (float*)(smem + 43648);                 // [64][9]   f32

    int tid = threadIdx.x;
    int row0 = blockIdx.x*64;
    int wave = tid>>6, lane = tid&63, l15 = lane&15, lq = lane>>4;
    const f32x4 zz = {0.f,0.f,0.f,0.f};

    // ======== FRONT MLP ========
    {   // stage X; zero K-pad (NaN*0 hazard)
        int r = tid >> 2, q = tid & 3;
        const float4* xp = (const float4*)(x + (row0 + r)*16 + q*4);
        float4 v = xp[0];
        *(float4*)(XS + r*36 + q*4) = v;
        *(float4*)(XS + r*36 + 16 + q*4) = make_float4(0.f,0.f,0.f,0.f);
    }
    __syncthreads();

    // GEMM1: Y1[64x128] = X[64x16] @ W1^T (x kept hi/lo); epi -> f16 H1.
    {
        f32x4 acc1[4][2];
        #pragma unroll
        for (int mt=0;mt<4;++mt){ acc1[mt][0]=zz; acc1[mt][1]=zz; }
        #pragma unroll
        for (int mt=0; mt<4; ++mt){
            f16x8 ah, al;
            split8(XS + (mt*16+l15)*36 + lq*8, ah, al);
            #pragma unroll
            for (int t=0;t<2;++t){
                int nt = wave + t*4;
                f16x8 b = *(const f16x8*)(H1w + (nt*16+l15)*32 + lq*8);
                acc1[mt][t] = __builtin_amdgcn_mfma_f32_16x16x32_f16(ah, b, acc1[mt][t], 0,0,0);
                acc1[mt][t] = __builtin_amdgcn_mfma_f32_16x16x32_f16(al, b, acc1[mt][t], 0,0,0);
            }
        }
        // H1 (@0) disjoint from XS (@26624): no barrier needed before stores.
        #pragma unroll
        for (int t=0;t<2;++t){
            int n = (wave + t*4)*16 + l15;
            float bias = c1[n];
            #pragma unroll
            for (int mt=0; mt<4; ++mt)
                #pragma unroll
                for (int reg=0; reg<4; ++reg){
                    int rowl = mt*16 + lq*4 + reg;
                    H1[rowl*136 + n] = f2h(fmaxf(acc1[mt][t][reg] + bias, 0.f));
                }
        }
    }
    __syncthreads();

    // GEMM2: Y2[64x64] = H1[64x128] @ W2^T, plain f16 A (R9: no hi/lo)
    {
        f32x4 acc2[4];
        #pragma unroll
        for (int mt=0;mt<4;++mt) acc2[mt]=zz;
        #pragma unroll
        for (int ks=0; ks<4; ++ks){
            f16x8 b = *(const f16x8*)(H2w + (wave*16+l15)*128 + ks*32 + lq*8);
            #pragma unroll
            for (int mt=0; mt<4; ++mt){
                f16x8 a = *(const f16x8*)(H1 + (mt*16+l15)*136 + ks*32 + lq*8);
                acc2[mt] = __builtin_amdgcn_mfma_f32_16x16x32_f16(a, b, acc2[mt], 0,0,0);
            }
        }
        int n = wave*16 + l15;
        float bias = c2[n];
        #pragma unroll
        for (int mt=0; mt<4; ++mt)
            #pragma unroll
            for (int reg=0; reg<4; ++reg){
                int rowl = mt*16 + lq*4 + reg;
                H2[rowl*72 + n] = f2h(fmaxf(acc2[mt][reg] + bias, 0.f));
            }
    }
    __syncthreads();

    // GEMM3: pre[64x8] = H2[64x64] @ W3^T (N pad 16), plain f16 A
    {
        f32x4 acc3 = zz;
        #pragma unroll
        for (int ks=0; ks<2; ++ks){
            f16x8 b = *(const f16x8*)(H3w + l15*64 + ks*32 + lq*8);
            f16x8 a = *(const f16x8*)(H2 + (wave*16+l15)*72 + ks*32 + lq*8);
            acc3 = __builtin_amdgcn_mfma_f32_16x16x32_f16(a, b, acc3, 0,0,0);
        }
        if (l15 < 8){
            float bias = b3[l15];
            #pragma unroll
            for (int reg=0; reg<4; ++reg){
                int rowl = wave*16 + lq*4 + reg;
                preL[rowl*8 + l15] = tanhf(acc3[reg] + bias);
            }
        }
    }
    __syncthreads();

    // ======== EXPAND s0 (RY^T encoding: bit=1 factor = -sin) ========
    // As (@0..33792) overlaps only dead regions (H1,H2,XS); preL disjoint.
    {
        int row = tid & 63, q = tid >> 6;         // q = bits7..6 of amplitude index
        const float4* p4 = (const float4*)(preL + row*8);
        float4 pa = p4[0], pb = p4[1];
        float th[8] = {pa.x,pa.y,pa.z,pa.w,pb.x,pb.y,pb.z,pb.w};
        float cs[8], sn[8];
        #pragma unroll
        for (int i=0;i<8;++i){ __sincosf(0.5f*th[i], &sn[i], &cs[i]); sn[i] = -sn[i]; }
        float F = (q&2 ? sn[0] : cs[0]) * (q&1 ? sn[1] : cs[1]);
        float Pm[8], Pl[8];
        #pragma unroll
        for (int a2=0;a2<8;++a2){
            Pm[a2] = (a2&4?sn[2]:cs[2]) * (a2&2?sn[3]:cs[3]) * (a2&1?sn[4]:cs[4]);
            Pl[a2] = (a2&4?sn[5]:cs[5]) * (a2&2?sn[6]:cs[6]) * (a2&1?sn[7]:cs[7]);
        }
        unsigned short* arow = As + row*A_STRIDE + q*64;
        #pragma unroll
        for (int mh=0;mh<8;++mh){
            float fm = F * Pm[mh];
            uint4 w;
            w.x = (unsigned)f2h(fm*Pl[0]) | ((unsigned)f2h(fm*Pl[1])<<16);
            w.y = (unsigned)f2h(fm*Pl[2]) | ((unsigned)f2h(fm*Pl[3])<<16);
            w.z = (unsigned)f2h(fm*Pl[4]) | ((unsigned)f2h(fm*Pl[5])<<16);
            w.w = (unsigned)f2h(fm*Pl[6]) | ((unsigned)f2h(fm*Pl[7])<<16);
            *reinterpret_cast<uint4*>(arow + mh*8) = w;
        }
    }
    __syncthreads();

    // ======== QUANTUM GEMM: C[64x512] = A[64x256] @ Wq^T ========
    const f16x8* Bp[8];
    #pragma unroll
    for (int t=0;t<8;++t){
        int T = ((t>>2)<<4) + wave*4 + (t&3);   // t 0-3: Re, 4-7: Im (+16)
        Bp[t] = reinterpret_cast<const f16x8*>(WqS + T*4096) + lane;
    }
    const f16x8* Ap[4];
    #pragma unroll
    for (int mt=0;mt<4;++mt)
        Ap[mt] = reinterpret_cast<const f16x8*>(As + (mt*16 + l15)*A_STRIDE + lq*8);

    f32x4 acc[4][8];
    #pragma unroll
    for (int mt=0;mt<4;++mt)
        #pragma unroll
        for (int t=0;t<8;++t) acc[mt][t] = zz;

    f16x8 bfr[2][8];
    #pragma unroll
    for (int t=0;t<8;++t) bfr[0][t] = Bp[t][0];

    #pragma unroll
    for (int ks=0;ks<8;++ks){
        int cur = ks & 1;
        if (ks < 7){
            #pragma unroll
            for (int t=0;t<8;++t) bfr[cur^1][t] = Bp[t][(ks+1)*64];  // next 4KB block
        }
        f16x8 afr[4];
        #pragma unroll
        for (int mt=0;mt<4;++mt) afr[mt] = Ap[mt][ks*4];
        #pragma unroll
        for (int mt=0;mt<4;++mt)
            #pragma unroll
            for (int t=0;t<8;++t)
                acc[mt][t] = __builtin_amdgcn_mfma_f32_16x16x32_f16(afr[mt], bfr[cur][t], acc[mt][t], 0, 0, 0);
    }
    __syncthreads();   // A-tile dead; LDS reused for probs

    // ======== probs -> <Z_i> (256-thread reduction, stride-9) -> back MLP ===
    #pragma unroll
    for (int h=0; h<2; ++h){
        #pragma unroll
        for (int mtl=0; mtl<2; ++mtl){
            int mt = h*2 + mtl;
            #pragma unroll
            for (int t=0;t<4;++t){
                #pragma unroll
                for (int reg=0;reg<4;++reg){
                    float sr = acc[mt][t][reg];
                    float si = acc[mt][t+4][reg];
                    int prow = mtl*16 + lq*4 + reg;           // local row 0..31
                    int pcol = wave*64 + t*16 + l15;          // amplitude index 0..255
                    probs[prow*P_STRIDE + pcol] = fmaf(sr,sr,si*si);
                }
            }
        }
        __syncthreads();
        {   // 256 threads: row = tid&31, col-group q = tid>>5 (32 cols each)
            int row = tid & 31, q = tid >> 5;
            const float* pb = probs + row*P_STRIDE + q*32;
            float S=0.f,z3=0.f,z4=0.f,z5=0.f,z6=0.f,z7=0.f;
            #pragma unroll
            for (int j=0;j<32;++j){
                float p = pb[j];
                S  += p;
                z3 += (j&16)? -p : p;   // qubit3 <-> bit4
                z4 += (j&8) ? -p : p;
                z5 += (j&4) ? -p : p;
                z6 += (j&2) ? -p : p;
                z7 += (j&1) ? -p : p;
            }
            float* qa = qacc + (q*32 + row)*9;
            qa[0] = (q&4)? -S : S;    // qubit0 <-> bit7 (q bit2)
            qa[1] = (q&2)? -S : S;    // qubit1 <-> bit6 (q bit1)
            qa[2] = (q&1)? -S : S;    // qubit2 <-> bit5 (q bit0)
            qa[3] = z3; qa[4] = z4; qa[5] = z5; qa[6] = z6; qa[7] = z7;
        }
        __syncthreads();
        {   // combine 8 col-group partials -> qout
            int r = tid >> 3, i = tid & 7;
            float v = 0.f;
            #pragma unroll
            for (int g=0; g<8; ++g) v += qacc[(g*32 + r)*9 + i];
            qout[(h*32 + r)*9 + i] = v;
        }
    }
    __syncthreads();

    if (tid < 64){
        int r = tid;
        float qv[8];
        #pragma unroll
        for (int i=0;i<8;++i) qv[i] = qout[r*9+i];
        float h4[32];
        #pragma unroll
        for (int j=0;j<32;++j){
            float a = b4[j];
            #pragma unroll
            for (int i=0;i<8;++i) a = fmaf(qv[i], W4[j*8+i], a);
            float sc = g4[j]*rsqrtf(v4[j]+1e-5f);
            a = fmaf(a - m4[j], sc, bt4[j]);
            h4[j] = fmaxf(a, 0.f);
        }
        float h5[16];
        #pragma unroll
        for (int j=0;j<16;++j){
            float a = b5[j];
            #pragma unroll
            for (int k=0;k<32;++k) a = fmaf(h4[k], W5[j*32+k], a);
            h5[j] = fmaxf(a, 0.f);
        }
        float o = b6[0];
        #pragma unroll
        for (int k=0;k<16;++k) o = fmaf(h5[k], W6[k], o);
        out[blockIdx.x*64 + r] = o;
    }
}

// ---------- launch ----------
extern "C" void kernel_launch(void* const* d_in, const int* in_sizes, int n_in,
                              void* d_out, int out_size, void* d_ws, size_t ws_size,
                              hipStream_t stream) {
    (void)in_sizes; (void)n_in; (void)out_size; (void)ws_size;
    const float* x   = (const float*)d_in[0];
    const float* W1  = (const float*)d_in[1];
    const float* b1  = (const float*)d_in[2];
    const float* g1  = (const float*)d_in[3];
    const float* bt1 = (const float*)d_in[4];
    const float* m1  = (const float*)d_in[5];
    const float* v1  = (const float*)d_in[6];
    const float* W2  = (const float*)d_in[7];
    const float* b2  = (const float*)d_in[8];
    const float* g2  = (const float*)d_in[9];
    const float* bt2 = (const float*)d_in[10];
    const float* m2  = (const float*)d_in[11];
    const float* v2  = (const float*)d_in[12];
    const float* W3  = (const float*)d_in[13];
    const float* b3  = (const float*)d_in[14];
    const float* qw  = (const float*)d_in[15];
    const float* W4  = (const float*)d_in[16];
    const float* b4  = (const float*)d_in[17];
    const float* g4  = (const float*)d_in[18];
    const float* bt4 = (const float*)d_in[19];
    const float* m4  = (const float*)d_in[20];
    const float* v4  = (const float*)d_in[21];
    const float* W5  = (const float*)d_in[22];
    const float* b5  = (const float*)d_in[23];
    const float* W6  = (const float*)d_in[24];
    const float* b6  = (const float*)d_in[25];

    char* ws = (char*)d_ws;
    float2* U   = (float2*)ws;                            // 2 * 65536 float2 (1 MB)
    unsigned short* WqS = (unsigned short*)(U + 2*65536); // 512*256 f16 swizzled (0.25 MB)
    unsigned short* H1w = WqS + 512*256;                  // 128*32 f16
    unsigned short* H2w = H1w + 4096;                     // 64*128 f16
    unsigned short* H3w = H2w + 8192;                     // 16*64 f16
    float* c1 = (float*)(H3w + 1024);                     // 128 f32
    float* c2 = c1 + 128;                                 // 64 f32

    k_build_prep<<<dim3(256,3), 256, 0, stream>>>(qw, U,
                                  W1,b1,g1,bt1,m1,v1, W2,b2,g2,bt2,m2,v2, W3,
                                  H1w,c1,H2w,c2,H3w);
    k_rowmm<<<256, 256, 0, stream>>>(qw, U, WqS);          // WqS = swizzled [Re;Im](U3*U2*U1)
    k_fused<<<1024, 256, 0, stream>>>(x, H1w,c1, H2w,c2, H3w,b3, WqS,
                                      W4,b4,g4,bt4,m4,v4, W5,b5,W6,b6,
                                      (float*)d_out);
}

// Round 10
// 174.403 us; speedup vs baseline: 1.5145x; 1.5145x over previous
//
#include <hip/hip_runtime.h>

// ---------- helpers ----------
__device__ __forceinline__ float2 cmul(float2 a, float2 b){
    return make_float2(a.x*b.x - a.y*b.y, a.x*b.y + a.y*b.x);
}
__device__ __forceinline__ float2 cadd(float2 a, float2 b){
    return make_float2(a.x + b.x, a.y + b.y);
}
__device__ __forceinline__ unsigned short f2h(float f){
    _Float16 h = (_Float16)f;                    // v_cvt_f16_f32, round-nearest
    return __builtin_bit_cast(unsigned short, h);
}

typedef _Float16 f16x8 __attribute__((ext_vector_type(8)));
typedef float    f32x4 __attribute__((ext_vector_type(4)));

// hi/lo fp16 split of 8 contiguous f32 from LDS (kept only for the x input).
__device__ __forceinline__ void split8(const float* p, f16x8& ah, f16x8& al){
    const f32x4* q = (const f32x4*)p;
    f32x4 v0 = q[0], v1 = q[1];
    float av[8] = {v0[0],v0[1],v0[2],v0[3],v1[0],v1[1],v1[2],v1[3]};
    #pragma unroll
    for (int j=0;j<8;++j){
        _Float16 h = (_Float16)av[j];
        ah[j] = h;
        al[j] = (_Float16)(av[j] - (float)h);
    }
}

// Effective per-qubit operator (reference einsum applies U^T):
// G = RZ * RY(-t) * RX.
__device__ __forceinline__ void build_gates(const float* qw, int l, int c, float2 (*G)[2][2]){
    if (c < 8){
        int i = c;
        float t0 = 0.5f*qw[l*24 + i*3 + 0];
        float t1 = 0.5f*qw[l*24 + i*3 + 1];
        float t2 = 0.5f*qw[l*24 + i*3 + 2];
        float c1,s1,c2,s2,c3,s3;
        sincosf(t0,&s1,&c1); sincosf(t1,&s2,&c2); sincosf(t2,&s3,&c3);
        float2 RX[2][2] = {{{c1,0.f},{0.f,-s1}},{{0.f,-s1},{c1,0.f}}};
        // RY^T (transposed: sine sign flipped)
        float2 RY[2][2] = {{{c2,0.f},{s2,0.f}},{{-s2,0.f},{c2,0.f}}};
        float2 M[2][2];
        #pragma unroll
        for (int r=0;r<2;++r)
            #pragma unroll
            for (int cc=0;cc<2;++cc)
                M[r][cc] = cadd(cmul(RY[r][0],RX[0][cc]), cmul(RY[r][1],RX[1][cc]));
        float2 e  = {c3,-s3};
        float2 ec = {c3, s3};
        G[i][0][0]=cmul(e, M[0][0]); G[i][0][1]=cmul(e, M[0][1]);
        G[i][1][0]=cmul(ec,M[1][0]); G[i][1][1]=cmul(ec,M[1][1]);
    }
}
__device__ __forceinline__ int cnot_perm(int k){
    int r = k;
    for (int i=6;i>=0;--i)
        for (int j=7;j>i;--j)
            if ((r >> (7-i)) & 1) r ^= 1 << (7-j);
    return r;
}

// ---------- K1: build layer-0/1 operators + (y==2) BN-folded weight prep ----
__global__ void k_build_prep(const float* __restrict__ qw, float2* __restrict__ U,
                       const float* __restrict__ W1, const float* __restrict__ b1,
                       const float* __restrict__ g1, const float* __restrict__ bt1,
                       const float* __restrict__ m1, const float* __restrict__ v1,
                       const float* __restrict__ W2, const float* __restrict__ b2,
                       const float* __restrict__ g2, const float* __restrict__ bt2,
                       const float* __restrict__ m2, const float* __restrict__ v2,
                       const float* __restrict__ W3,
                       unsigned short* __restrict__ H1w, float* __restrict__ c1,
                       unsigned short* __restrict__ H2w, float* __restrict__ c2,
                       unsigned short* __restrict__ H3w){
    if (blockIdx.y == 2){
        if (blockIdx.x >= 8) return;
        int tid = blockIdx.x*256 + threadIdx.x;
        const int stride = 8*256;
        for (int i=tid; i<4096; i+=stride){ int n=i>>5, k=i&31;
            float s=g1[n]*rsqrtf(v1[n]+1e-5f);
            H1w[i] = f2h(k<16 ? W1[n*16+k]*s : 0.f); }
        for (int i=tid; i<128;  i+=stride){ float s=g1[i]*rsqrtf(v1[i]+1e-5f); c1[i]=(b1[i]-m1[i])*s+bt1[i]; }
        for (int i=tid; i<8192; i+=stride){ int n=i>>7;
            float s=g2[n]*rsqrtf(v2[n]+1e-5f);
            H2w[i] = f2h(W2[i]*s); }
        for (int i=tid; i<64;   i+=stride){ float s=g2[i]*rsqrtf(v2[i]+1e-5f); c2[i]=(b2[i]-m2[i])*s+bt2[i]; }
        for (int i=tid; i<1024; i+=stride){ int n=i>>6, k=i&63;
            H3w[i] = f2h(n<8 ? W3[n*64+k] : 0.f); }
        return;
    }
    __shared__ float2 G[8][2][2];
    int l = blockIdx.y, k = blockIdx.x, c = threadIdx.x;
    build_gates(qw, l, c, G);
    __syncthreads();
    int r = cnot_perm(k);
    float2 p = {1.f, 0.f};
    #pragma unroll
    for (int i=0;i<8;++i)
        p = cmul(p, G[i][(r>>(7-i))&1][(c>>(7-i))&1]);
    U[l*65536 + k*256 + c] = p;
}

// ---------- K2: per-row W = row_r(U3*U2*U1) -> fp16, FRAGMENT-SWIZZLED ------
// element (n,k) -> WqS[((T*8+ks)*64 + lane)*8 + j]; a wave's B-load is then
// base + lane*16B: one contiguous 1KB burst (R7: cut k_main 66->51us).
__global__ __launch_bounds__(256) void k_rowmm(const float* __restrict__ qw,
                                              const float2* __restrict__ U,
                                              unsigned short* __restrict__ WqS){
    __shared__ float2 G[8][2][2];
    __shared__ float2 vs[256];
    __shared__ float2 ws[256];
    int r = blockIdx.x, c = threadIdx.x;
    build_gates(qw, 2, c, G);
    __syncthreads();
    int pr = cnot_perm(r);
    float2 p = {1.f, 0.f};
    #pragma unroll
    for (int i=0;i<8;++i)
        p = cmul(p, G[i][(pr>>(7-i))&1][(c>>(7-i))&1]);
    vs[c] = p;
    __syncthreads();
    float2 acc = {0.f,0.f};
    #pragma unroll 8
    for (int m=0;m<256;++m)
        acc = cadd(acc, cmul(vs[m], U[65536 + m*256 + c]));   // U2
    ws[c] = acc;
    __syncthreads();
    float2 z = {0.f,0.f};
    #pragma unroll 8
    for (int m=0;m<256;++m)
        z = cadd(z, cmul(ws[m], U[m*256 + c]));               // U1
    int T = r >> 4, l15 = r & 15;
    int ks = c >> 5, lq = (c >> 3) & 3, j = c & 7;
    int lane = lq*16 + l15;
    WqS[((T     *8 + ks)*64 + lane)*8 + j] = f2h(z.x);   // Re tiles 0..15
    WqS[(((T+16)*8 + ks)*64 + lane)*8 + j] = f2h(z.y);   // Im tiles 16..31
}

// ---------- K3: FUSED front MLP + s0-expand + quantum GEMM + Z + back MLP --
// 1024 wgs x 256 thr, 64 batch rows/wg. 44.9 KB arena.
// R9 post-mortem: __launch_bounds__(256,3) capped VGPR at 84 -> the 128-VGPR
// quantum-GEMM accumulator spilled to scratch (FETCH 108MB, WRITE 247MB,
// 145us). Bound reverted to 2: allocator free (~128 VGPR, no spill); HW can
// still co-schedule 3 wgs/CU from actual usage (LDS 3x46KB=138<160KB).
// front: H1@0 [64][136]f16, H2@17408 [64][72]f16, XS@26624 [64][36]f32,
//        preL@35840 [64][8]f32
// main:  As@0 [64][264]f16; probs@0 [32][269]f32; qacc@34432 [256][9]f32
//        (stride 9: coprime w/ 32 banks); qout@43648 [64][9]f32.
#define A_STRIDE 264
#define P_STRIDE 269
__global__ __launch_bounds__(256,2) void k_fused(
    const float* __restrict__ x,
    const unsigned short* __restrict__ H1w, const float* __restrict__ c1,
    const unsigned short* __restrict__ H2w, const float* __restrict__ c2,
    const unsigned short* __restrict__ H3w, const float* __restrict__ b3,
    const unsigned short* __restrict__ WqS,
    const float* __restrict__ W4, const float* __restrict__ b4, const float* __restrict__ g4,
    const float* __restrict__ bt4, const float* __restrict__ m4, const float* __restrict__ v4,
    const float* __restrict__ W5, const float* __restrict__ b5,
    const float* __restrict__ W6, const float* __restrict__ b6,
    float* __restrict__ out)
{
    __shared__ __align__(16) char smem[45952];
    unsigned short* H1 = (unsigned short*)smem;            // [64][136] f16
    unsigned short* H2 = (unsigned short*)(smem + 17408);  // [64][72]  f16
    float* XS   = (float*)(smem + 26624);                  // [64][36]  f32
    float* preL = (float*)(smem + 35840);                  // [64][8]   f32
    unsigned short* As = (unsigned short*)smem;            // [64][264] f16
    float* probs = (float*)smem;                           // [32][269] f32
    float* qacc  = (float*)(smem + 34432);                 // [256][9]  f32
    float* qout  = (float*)(smem + 43648);                 // [64][9]   f32

    int tid = threadIdx.x;
    int row0 = blockIdx.x*64;
    int wave = tid>>6, lane = tid&63, l15 = lane&15, lq = lane>>4;
    const f32x4 zz = {0.f,0.f,0.f,0.f};

    // ======== FRONT MLP ========
    {   // stage X; zero K-pad (NaN*0 hazard)
        int r = tid >> 2, q = tid & 3;
        const float4* xp = (const float4*)(x + (row0 + r)*16 + q*4);
        float4 v = xp[0];
        *(float4*)(XS + r*36 + q*4) = v;
        *(float4*)(XS + r*36 + 16 + q*4) = make_float4(0.f,0.f,0.f,0.f);
    }
    __syncthreads();

    // GEMM1: Y1[64x128] = X[64x16] @ W1^T (x kept hi/lo); epi -> f16 H1.
    {
        f32x4 acc1[4][2];
        #pragma unroll
        for (int mt=0;mt<4;++mt){ acc1[mt][0]=zz; acc1[mt][1]=zz; }
        #pragma unroll
        for (int mt=0; mt<4; ++mt){
            f16x8 ah, al;
            split8(XS + (mt*16+l15)*36 + lq*8, ah, al);
            #pragma unroll
            for (int t=0;t<2;++t){
                int nt = wave + t*4;
                f16x8 b = *(const f16x8*)(H1w + (nt*16+l15)*32 + lq*8);
                acc1[mt][t] = __builtin_amdgcn_mfma_f32_16x16x32_f16(ah, b, acc1[mt][t], 0,0,0);
                acc1[mt][t] = __builtin_amdgcn_mfma_f32_16x16x32_f16(al, b, acc1[mt][t], 0,0,0);
            }
        }
        // H1 (@0) disjoint from XS (@26624): no barrier needed before stores.
        #pragma unroll
        for (int t=0;t<2;++t){
            int n = (wave + t*4)*16 + l15;
            float bias = c1[n];
            #pragma unroll
            for (int mt=0; mt<4; ++mt)
                #pragma unroll
                for (int reg=0; reg<4; ++reg){
                    int rowl = mt*16 + lq*4 + reg;
                    H1[rowl*136 + n] = f2h(fmaxf(acc1[mt][t][reg] + bias, 0.f));
                }
        }
    }
    __syncthreads();

    // GEMM2: Y2[64x64] = H1[64x128] @ W2^T, plain f16 A
    {
        f32x4 acc2[4];
        #pragma unroll
        for (int mt=0;mt<4;++mt) acc2[mt]=zz;
        #pragma unroll
        for (int ks=0; ks<4; ++ks){
            f16x8 b = *(const f16x8*)(H2w + (wave*16+l15)*128 + ks*32 + lq*8);
            #pragma unroll
            for (int mt=0; mt<4; ++mt){
                f16x8 a = *(const f16x8*)(H1 + (mt*16+l15)*136 + ks*32 + lq*8);
                acc2[mt] = __builtin_amdgcn_mfma_f32_16x16x32_f16(a, b, acc2[mt], 0,0,0);
            }
        }
        int n = wave*16 + l15;
        float bias = c2[n];
        #pragma unroll
        for (int mt=0; mt<4; ++mt)
            #pragma unroll
            for (int reg=0; reg<4; ++reg){
                int rowl = mt*16 + lq*4 + reg;
                H2[rowl*72 + n] = f2h(fmaxf(acc2[mt][reg] + bias, 0.f));
            }
    }
    __syncthreads();

    // GEMM3: pre[64x8] = H2[64x64] @ W3^T (N pad 16), plain f16 A
    {
        f32x4 acc3 = zz;
        #pragma unroll
        for (int ks=0; ks<2; ++ks){
            f16x8 b = *(const f16x8*)(H3w + l15*64 + ks*32 + lq*8);
            f16x8 a = *(const f16x8*)(H2 + (wave*16+l15)*72 + ks*32 + lq*8);
            acc3 = __builtin_amdgcn_mfma_f32_16x16x32_f16(a, b, acc3, 0,0,0);
        }
        if (l15 < 8){
            float bias = b3[l15];
            #pragma unroll
            for (int reg=0; reg<4; ++reg){
                int rowl = wave*16 + lq*4 + reg;
                preL[rowl*8 + l15] = tanhf(acc3[reg] + bias);
            }
        }
    }
    __syncthreads();

    // ======== EXPAND s0 (RY^T encoding: bit=1 factor = -sin) ========
    // As (@0..33792) overlaps only dead regions (H1,H2,XS); preL disjoint.
    {
        int row = tid & 63, q = tid >> 6;         // q = bits7..6 of amplitude index
        const float4* p4 = (const float4*)(preL + row*8);
        float4 pa = p4[0], pb = p4[1];
        float th[8] = {pa.x,pa.y,pa.z,pa.w,pb.x,pb.y,pb.z,pb.w};
        float cs[8], sn[8];
        #pragma unroll
        for (int i=0;i<8;++i){ __sincosf(0.5f*th[i], &sn[i], &cs[i]); sn[i] = -sn[i]; }
        float F = (q&2 ? sn[0] : cs[0]) * (q&1 ? sn[1] : cs[1]);
        float Pm[8], Pl[8];
        #pragma unroll
        for (int a2=0;a2<8;++a2){
            Pm[a2] = (a2&4?sn[2]:cs[2]) * (a2&2?sn[3]:cs[3]) * (a2&1?sn[4]:cs[4]);
            Pl[a2] = (a2&4?sn[5]:cs[5]) * (a2&2?sn[6]:cs[6]) * (a2&1?sn[7]:cs[7]);
        }
        unsigned short* arow = As + row*A_STRIDE + q*64;
        #pragma unroll
        for (int mh=0;mh<8;++mh){
            float fm = F * Pm[mh];
            uint4 w;
            w.x = (unsigned)f2h(fm*Pl[0]) | ((unsigned)f2h(fm*Pl[1])<<16);
            w.y = (unsigned)f2h(fm*Pl[2]) | ((unsigned)f2h(fm*Pl[3])<<16);
            w.z = (unsigned)f2h(fm*Pl[4]) | ((unsigned)f2h(fm*Pl[5])<<16);
            w.w = (unsigned)f2h(fm*Pl[6]) | ((unsigned)f2h(fm*Pl[7])<<16);
            *reinterpret_cast<uint4*>(arow + mh*8) = w;
        }
    }
    __syncthreads();

    // ======== QUANTUM GEMM: C[64x512] = A[64x256] @ Wq^T ========
    const f16x8* Bp[8];
    #pragma unroll
    for (int t=0;t<8;++t){
        int T = ((t>>2)<<4) + wave*4 + (t&3);   // t 0-3: Re, 4-7: Im (+16)
        Bp[t] = reinterpret_cast<const f16x8*>(WqS + T*4096) + lane;
    }
    const f16x8* Ap[4];
    #pragma unroll
    for (int mt=0;mt<4;++mt)
        Ap[mt] = reinterpret_cast<const f16x8*>(As + (mt*16 + l15)*A_STRIDE + lq*8);

    f32x4 acc[4][8];
    #pragma unroll
    for (int mt=0;mt<4;++mt)
        #pragma unroll
        for (int t=0;t<8;++t) acc[mt][t] = zz;

    f16x8 bfr[2][8];
    #pragma unroll
    for (int t=0;t<8;++t) bfr[0][t] = Bp[t][0];

    #pragma unroll
    for (int ks=0;ks<8;++ks){
        int cur = ks & 1;
        if (ks < 7){
            #pragma unroll
            for (int t=0;t<8;++t) bfr[cur^1][t] = Bp[t][(ks+1)*64];  // next 4KB block
        }
        f16x8 afr[4];
        #pragma unroll
        for (int mt=0;mt<4;++mt) afr[mt] = Ap[mt][ks*4];
        #pragma unroll
        for (int mt=0;mt<4;++mt)
            #pragma unroll
            for (int t=0;t<8;++t)
                acc[mt][t] = __builtin_amdgcn_mfma_f32_16x16x32_f16(afr[mt], bfr[cur][t], acc[mt][t], 0, 0, 0);
    }
    __syncthreads();   // A-tile dead; LDS reused for probs

    // ======== probs -> <Z_i> (256-thread reduction, stride-9) -> back MLP ===
    #pragma unroll
    for (int h=0; h<2; ++h){
        #pragma unroll
        for (int mtl=0; mtl<2; ++mtl){
            int mt = h*2 + mtl;
            #pragma unroll
            for (int t=0;t<4;++t){
                #pragma unroll
                for (int reg=0;reg<4;++reg){
                    float sr = acc[mt][t][reg];
                    float si = acc[mt][t+4][reg];
                    int prow = mtl*16 + lq*4 + reg;           // local row 0..31
                    int pcol = wave*64 + t*16 + l15;          // amplitude index 0..255
                    probs[prow*P_STRIDE + pcol] = fmaf(sr,sr,si*si);
                }
            }
        }
        __syncthreads();
        {   // 256 threads: row = tid&31, col-group q = tid>>5 (32 cols each)
            int row = tid & 31, q = tid >> 5;
            const float* pb = probs + row*P_STRIDE + q*32;
            float S=0.f,z3=0.f,z4=0.f,z5=0.f,z6=0.f,z7=0.f;
            #pragma unroll
            for (int j=0;j<32;++j){
                float p = pb[j];
                S  += p;
                z3 += (j&16)? -p : p;   // qubit3 <-> bit4
                z4 += (j&8) ? -p : p;
                z5 += (j&4) ? -p : p;
                z6 += (j&2) ? -p : p;
                z7 += (j&1) ? -p : p;
            }
            float* qa = qacc + (q*32 + row)*9;
            qa[0] = (q&4)? -S : S;    // qubit0 <-> bit7 (q bit2)
            qa[1] = (q&2)? -S : S;    // qubit1 <-> bit6 (q bit1)
            qa[2] = (q&1)? -S : S;    // qubit2 <-> bit5 (q bit0)
            qa[3] = z3; qa[4] = z4; qa[5] = z5; qa[6] = z6; qa[7] = z7;
        }
        __syncthreads();
        {   // combine 8 col-group partials -> qout
            int r = tid >> 3, i = tid & 7;
            float v = 0.f;
            #pragma unroll
            for (int g=0; g<8; ++g) v += qacc[(g*32 + r)*9 + i];
            qout[(h*32 + r)*9 + i] = v;
        }
    }
    __syncthreads();

    if (tid < 64){
        int r = tid;
        float qv[8];
        #pragma unroll
        for (int i=0;i<8;++i) qv[i] = qout[r*9+i];
        float h4[32];
        #pragma unroll
        for (int j=0;j<32;++j){
            float a = b4[j];
            #pragma unroll
            for (int i=0;i<8;++i) a = fmaf(qv[i], W4[j*8+i], a);
            float sc = g4[j]*rsqrtf(v4[j]+1e-5f);
            a = fmaf(a - m4[j], sc, bt4[j]);
            h4[j] = fmaxf(a, 0.f);
        }
        float h5[16];
        #pragma unroll
        for (int j=0;j<16;++j){
            float a = b5[j];
            #pragma unroll
            for (int k=0;k<32;++k) a = fmaf(h4[k], W5[j*32+k], a);
            h5[j] = fmaxf(a, 0.f);
        }
        float o = b6[0];
        #pragma unroll
        for (int k=0;k<16;++k) o = fmaf(h5[k], W6[k], o);
        out[blockIdx.x*64 + r] = o;
    }
}

// ---------- launch ----------
extern "C" void kernel_launch(void* const* d_in, const int* in_sizes, int n_in,
                              void* d_out, int out_size, void* d_ws, size_t ws_size,
                              hipStream_t stream) {
    (void)in_sizes; (void)n_in; (void)out_size; (void)ws_size;
    const float* x   = (const float*)d_in[0];
    const float* W1  = (const float*)d_in[1];
    const float* b1  = (const float*)d_in[2];
    const float* g1  = (const float*)d_in[3];
    const float* bt1 = (const float*)d_in[4];
    const float* m1  = (const float*)d_in[5];
    const float* v1  = (const float*)d_in[6];
    const float* W2  = (const float*)d_in[7];
    const float* b2  = (const float*)d_in[8];
    const float* g2  = (const float*)d_in[9];
    const float* bt2 = (const float*)d_in[10];
    const float* m2  = (const float*)d_in[11];
    const float* v2  = (const float*)d_in[12];
    const float* W3  = (const float*)d_in[13];
    const float* b3  = (const float*)d_in[14];
    const float* qw  = (const float*)d_in[15];
    const float* W4  = (const float*)d_in[16];
    const float* b4  = (const float*)d_in[17];
    const float* g4  = (const float*)d_in[18];
    const float* bt4 = (const float*)d_in[19];
    const float* m4  = (const float*)d_in[20];
    const float* v4  = (const float*)d_in[21];
    const float* W5  = (const float*)d_in[22];
    const float* b5  = (const float*)d_in[23];
    const float* W6  = (const float*)d_in[24];
    const float* b6  = (const float*)d_in[25];

    char* ws = (char*)d_ws;
    float2* U   = (float2*)ws;                            // 2 * 65536 float2 (1 MB)
    unsigned short* WqS = (unsigned short*)(U + 2*65536); // 512*256 f16 swizzled (0.25 MB)
    unsigned short* H1w = WqS + 512*256;                  // 128*32 f16
    unsigned short* H2w = H1w + 4096;                     // 64*128 f16
    unsigned short* H3w = H2w + 8192;                     // 16*64 f16
    float* c1 = (float*)(H3w + 1024);                     // 128 f32
    float* c2 = c1 + 128;                                 // 64 f32

    k_build_prep<<<dim3(256,3), 256, 0, stream>>>(qw, U,
                                  W1,b1,g1,bt1,m1,v1, W2,b2,g2,bt2,m2,v2, W3,
                                  H1w,c1,H2w,c2,H3w);
    k_rowmm<<<256, 256, 0, stream>>>(qw, U, WqS);          // WqS = swizzled [Re;Im](U3*U2*U1)
    k_fused<<<1024, 256, 0, stream>>>(x, H1w,c1, H2w,c2, H3w,b3, WqS,
                                      W4,b4,g4,bt4,m4,v4, W5,b5,W6,b6,
                                      (float*)d_out);
}